// Round 6
// baseline (3342.675 us; speedup 1.0000x reference)
//
#include <hip/hip_runtime.h>
#include <hip/hip_bf16.h>

// GRU: B=64 T=512 I=512 H=1024 M=8
// Partition: 4 teams (16 batch rows each) x 64 WGs (16 H-cols each).
// R6: 16B bypass transport + monotonic-counter team barrier -> 2950us.
// R7 (this round): h-broadcast through per-XCD L2 instead of all-MALL.
//   The 2-deep hbuf forced bypass READS (address reuse -> stale-L2 risk).
//   Replace with a NEVER-REUSED ring: 513 entries x 128KB (entry t = h input
//   of step t; step t writes entry t+1). Producers keep sc0 sc1 write-through
//   stores (LLC-visible across XCDs); readers use PLAIN CACHED loads — every
//   address is first-touched once per launch, so L1/L2 cannot be stale.
//   32 WGs/XCD now share one L2 copy: MALL requests 524K -> ~66K/step.
//   Cross-launch reuse is safe via dispatch-boundary agent acquire (L2 inv).

typedef __attribute__((ext_vector_type(8))) short short8_t;
typedef __attribute__((ext_vector_type(4))) float float4_t;
typedef __attribute__((ext_vector_type(4))) unsigned int uint4v;

#define T_STEPS 512

// workspace layout (bytes)
#define OFF_XBF  0ull
#define SZ_XBF   (64ull*512*512*2)            // 33,554,432
#define OFF_WH   (OFF_XBF + SZ_XBF)
#define SZ_WH    (64ull*3*32*64*8*2)          // 6,291,456
#define OFF_WX   (OFF_WH + SZ_WH)
#define SZ_WX    (64ull*3*16*64*8*2)          // 3,145,728
#define OFF_HRING (OFF_WX + SZ_WX)
#define SZ_HRING (513ull*64*1024*2)           // 67,239,936 (513 x [64 rows][2048B])
#define OFF_PART (OFF_HRING + SZ_HRING)
#define SZ_PART  (3ull*4*64*16*8*4)           // 393,216
#define OFF_CTR  (OFF_PART + SZ_PART)
#define SZ_CTR   4096ull                      // per-team monotonic ctr @ team*128B

// output layout (fp32 elements)
#define HN_OFF   (64ull*512*1024)             // 33,554,432
#define MP_OFF   (HN_OFF + 64ull*1024)        // 33,619,968

// LDS: whlds 98304 | cz/cr/chn/cxn 4096 | hloc 1024 | wmlds 512 | hlds 16*2064
#define HLDS_STRIDE 2064                      // 1032 shorts: breaks bank alias
#define SMEM_BYTES (98304 + 4096 + 1024 + 512 + 16*HLDS_STRIDE)

static __device__ __forceinline__ unsigned short f2bf(float f) {
    __hip_bfloat16 h = __float2bfloat16(f);
    unsigned short u;
    __builtin_memcpy(&u, &h, 2);
    return u;
}
static __device__ __forceinline__ unsigned ld_agent_u32(const unsigned* p) {
    return __hip_atomic_load(p, __ATOMIC_RELAXED, __HIP_MEMORY_SCOPE_AGENT);
}
// 16B LLC-coherent (L1/L2-bypass) store, fire-and-forget (drained by syncthreads)
static __device__ __forceinline__ void st_bypass_u128(void* p, uint4v v) {
    asm volatile("global_store_dwordx4 %0, %1, off sc0 sc1"
                 :: "v"(p), "v"(v) : "memory");
}
// 2x16B LLC-coherent loads, pipelined, one wait
static __device__ __forceinline__ void ld_bypass_2x128(const void* p0, const void* p1,
                                                       uint4v& a, uint4v& b) {
    asm volatile("global_load_dwordx4 %0, %2, off sc0 sc1\n\t"
                 "global_load_dwordx4 %1, %3, off sc0 sc1\n\t"
                 "s_waitcnt vmcnt(0)"
                 : "=&v"(a), "=&v"(b) : "v"(p0), "v"(p1) : "memory");
}

// ---- prep kernels ----------------------------------------------------------

__global__ void prep_x(const float* __restrict__ x, unsigned short* __restrict__ xbf) {
    const size_t i = ((size_t)blockIdx.x * 256 + threadIdx.x) * 4;
    const float4 v = *(const float4*)(x + i);
    ushort4 o = make_ushort4(f2bf(v.x), f2bf(v.y), f2bf(v.z), f2bf(v.w));
    *(ushort4*)(xbf + i) = o;
}

__global__ void prep_h0(const float* __restrict__ h0, unsigned short* __restrict__ hbuf) {
    const size_t i = ((size_t)blockIdx.x * 256 + threadIdx.x) * 4;   // 65,536 elems
    const float4 v = *(const float4*)(h0 + i);
    ushort4 o = make_ushort4(f2bf(v.x), f2bf(v.y), f2bf(v.z), f2bf(v.w));
    *(ushort4*)(hbuf + i) = o;
}

// whswz[((twg*3+g)*32+kt)*64+lane][j] = Wh[kt*32+(lane>>4)*8+j][g*1024+twg*16+(lane&15)]
__global__ void prep_wh_k(const float* __restrict__ Wh, unsigned short* __restrict__ whswz) {
    const int tid = blockIdx.x * 256 + threadIdx.x;   // 393,216 total
    const int lane = tid & 63;
    const int r = tid >> 6;
    const int kt = r & 31;
    const int r2 = r >> 5;            // twg*3+g
    const int g = r2 % 3;
    const int twg = r2 / 3;
    const int col = g * 1024 + twg * 16 + (lane & 15);
    const int k0 = kt * 32 + (lane >> 4) * 8;
    unsigned short tmp[8];
#pragma unroll
    for (int j = 0; j < 8; ++j) tmp[j] = f2bf(Wh[(size_t)(k0 + j) * 3072 + col]);
    ushort4* dst = (ushort4*)(whswz + (size_t)tid * 8);
    dst[0] = make_ushort4(tmp[0], tmp[1], tmp[2], tmp[3]);
    dst[1] = make_ushort4(tmp[4], tmp[5], tmp[6], tmp[7]);
}

__global__ void prep_wx_k(const float* __restrict__ Wx, unsigned short* __restrict__ wxswz) {
    const int tid = blockIdx.x * 256 + threadIdx.x;   // 196,608 total
    const int lane = tid & 63;
    const int r = tid >> 6;
    const int kt = r & 15;
    const int r2 = r >> 4;            // twg*3+g
    const int g = r2 % 3;
    const int twg = r2 / 3;
    const int col = g * 1024 + twg * 16 + (lane & 15);
    const int k0 = kt * 32 + (lane >> 4) * 8;
    unsigned short tmp[8];
#pragma unroll
    for (int j = 0; j < 8; ++j) tmp[j] = f2bf(Wx[(size_t)(k0 + j) * 3072 + col]);
    ushort4* dst = (ushort4*)(wxswz + (size_t)tid * 8);
    dst[0] = make_ushort4(tmp[0], tmp[1], tmp[2], tmp[3]);
    dst[1] = make_ushort4(tmp[4], tmp[5], tmp[6], tmp[7]);
}

// ---- persistent GRU kernel -------------------------------------------------

__global__ void __launch_bounds__(256, 1) gru_persistent(
    const unsigned short* __restrict__ xbf,
    const unsigned short* __restrict__ whswz,
    const unsigned short* __restrict__ wxswz,
    unsigned short* __restrict__ hring,
    unsigned long long* __restrict__ part64,
    unsigned int* __restrict__ flags,
    const float* __restrict__ h0,
    const float* __restrict__ bvec,
    const float* __restrict__ wm,
    const float* __restrict__ bm,
    float* __restrict__ out)
{
    extern __shared__ char smem[];
    unsigned short* whlds = (unsigned short*)smem;          // 49,152 ushorts
    float* cz    = (float*)(smem + 98304);                  // [16][16]
    float* cr    = cz + 256;
    float* chn   = cr + 256;
    float* cxn   = chn + 256;
    float* hloc  = cxn + 256;                               // [16][16] fp32 h slice
    float* wmlds = hloc + 256;                              // [16][8]
    char*  hlds  = smem + 98304 + 4096 + 1024 + 512;        // 16 rows x HLDS_STRIDE

    const int wg   = blockIdx.x;
    const int team = wg & 3;
    const int twg  = wg >> 2;
    const int tid  = threadIdx.x;
    const int wave = tid >> 6;
    const int lane = tid & 63;
    const int quad = lane >> 4;
    const int lrow = lane & 15;
    const int b0   = team * 16;
    const int colg = twg * 16 + (tid & 15);

    // one-time LDS setup
    {
        const uint4* src = (const uint4*)(whswz + (size_t)twg * 49152);
        uint4* dst = (uint4*)whlds;
        for (int i = tid; i < 6144; i += 256) dst[i] = src[i];
    }
    if (tid < 128) wmlds[tid] = wm[(twg * 16 + (tid >> 3)) * 8 + (tid & 7)];
    hloc[tid] = h0[(size_t)(b0 + (tid >> 4)) * 1024 + colg];
    const float bz = bvec[colg], br = bvec[1024 + colg], bn = bvec[2048 + colg];
    __syncthreads();

    unsigned int* teamctr = flags + team * 32;      // 128B apart per team
    const int g = wave;                             // gate id for waves 0..2

    auto mp_reduce = [&](int tprev) {
        const int p = tprev % 3;
        const int row = twg;                  // caller guards twg<16
        const char* pbase = (const char*)part64
            + ((size_t)p * 4 + team) * 32768 + (size_t)lane * 512 + row * 32;
        uint4v qa, qb;
        ld_bypass_2x128(pbase, pbase + 16, qa, qb);
        float4 va, vb;
        va.x = __uint_as_float(qa.x); va.y = __uint_as_float(qa.y);
        va.z = __uint_as_float(qa.z); va.w = __uint_as_float(qa.w);
        vb.x = __uint_as_float(qb.x); vb.y = __uint_as_float(qb.y);
        vb.z = __uint_as_float(qb.z); vb.w = __uint_as_float(qb.w);
#pragma unroll
        for (int off = 1; off < 64; off <<= 1) {
            va.x += __shfl_xor(va.x, off); va.y += __shfl_xor(va.y, off);
            va.z += __shfl_xor(va.z, off); va.w += __shfl_xor(va.w, off);
            vb.x += __shfl_xor(vb.x, off); vb.y += __shfl_xor(vb.y, off);
            vb.z += __shfl_xor(vb.z, off); vb.w += __shfl_xor(vb.w, off);
        }
        if (lane == 0) {
            float v[8] = {va.x, va.y, va.z, va.w, vb.x, vb.y, vb.z, vb.w};
            float mx = -3.4e38f;
#pragma unroll
            for (int m = 0; m < 8; ++m) { v[m] += bm[m]; mx = fmaxf(mx, v[m]); }
            float s = 0.f;
#pragma unroll
            for (int m = 0; m < 8; ++m) { v[m] = expf(v[m] - mx); s += v[m]; }
            const float inv = 1.f / s;
            float* dst = out + MP_OFF + ((size_t)(b0 + row) * 512 + tprev) * 8;
#pragma unroll
            for (int m = 0; m < 8; ++m) dst[m] = v[m] * inv;
        }
    };

    for (int t = 0; t < T_STEPS; ++t) {
        float4_t acc0 = {0.f,0.f,0.f,0.f}, acc1 = {0.f,0.f,0.f,0.f};
        float4_t xacc0 = {0.f,0.f,0.f,0.f}, xacc1 = {0.f,0.f,0.f,0.f};

        // x-GEMM (h-independent) BEFORE the barrier wait — hides sync latency
        if (wave < 3) {
            const unsigned short* xrow = xbf + ((size_t)(b0 + lrow) * 512 + t) * 512 + quad * 8;
            const unsigned short* wxb  = wxswz + ((size_t)(twg * 3 + g) * 16 * 64 + lane) * 8;
#pragma unroll
            for (int kt = 0; kt < 16; kt += 2) {
                short8_t a0 = *(const short8_t*)(xrow + kt * 32);
                short8_t a1 = *(const short8_t*)(xrow + kt * 32 + 32);
                short8_t w0 = *(const short8_t*)(wxb + (size_t)kt * 512);
                short8_t w1 = *(const short8_t*)(wxb + (size_t)kt * 512 + 512);
                xacc0 = __builtin_amdgcn_mfma_f32_16x16x32_bf16(a0, w0, xacc0, 0, 0, 0);
                xacc1 = __builtin_amdgcn_mfma_f32_16x16x32_bf16(a1, w1, xacc1, 0, 0, 0);
            }
        }

        // team barrier: single monotonic counter, 1 polling lane per WG
        if (t > 0 && tid == 0) {
            const unsigned tgt = 64u * (unsigned)t;
            while (ld_agent_u32(teamctr) < tgt) { }
        }
        __syncthreads();   // sync A (also drains prev-step part/out stores)

        // stage this team's h slice (16 rows x 2048B) into LDS via PLAIN CACHED
        // loads — ring entry t is first-touch, L2 dedupes across 32 WGs/XCD
        {
            const char* sbase = (const char*)hring + (size_t)t * 131072
                              + (size_t)b0 * 2048 + (size_t)tid * 16;
            uint4v v0 = *(const uint4v*)(sbase + 0 * 4096);
            uint4v v1 = *(const uint4v*)(sbase + 1 * 4096);
            uint4v v2 = *(const uint4v*)(sbase + 2 * 4096);
            uint4v v3 = *(const uint4v*)(sbase + 3 * 4096);
            uint4v v4 = *(const uint4v*)(sbase + 4 * 4096);
            uint4v v5 = *(const uint4v*)(sbase + 5 * 4096);
            uint4v v6 = *(const uint4v*)(sbase + 6 * 4096);
            uint4v v7 = *(const uint4v*)(sbase + 7 * 4096);
            // global offset of v_i = tid*16 + i*4096 -> row = i*2 + (tid>>7),
            // col byte = (tid&127)*16  (2048B per row)
            char* d = hlds + (tid >> 7) * HLDS_STRIDE + (tid & 127) * 16;
            *(uint4v*)(d + 0 * 2 * HLDS_STRIDE) = v0;
            *(uint4v*)(d + 1 * 2 * HLDS_STRIDE) = v1;
            *(uint4v*)(d + 2 * 2 * HLDS_STRIDE) = v2;
            *(uint4v*)(d + 3 * 2 * HLDS_STRIDE) = v3;
            *(uint4v*)(d + 4 * 2 * HLDS_STRIDE) = v4;
            *(uint4v*)(d + 5 * 2 * HLDS_STRIDE) = v5;
            *(uint4v*)(d + 6 * 2 * HLDS_STRIDE) = v6;
            *(uint4v*)(d + 7 * 2 * HLDS_STRIDE) = v7;
        }
        __syncthreads();   // sync B

        if (wave < 3) {
            // h-GEMM: A-frags from padded LDS, B-frags LDS-resident
            const char* hrowp = hlds + lrow * HLDS_STRIDE + quad * 16;
            const unsigned short* whb = whlds + ((size_t)g * 32 * 64 + lane) * 8;
#pragma unroll
            for (int kt = 0; kt < 32; kt += 2) {
                short8_t a0 = *(const short8_t*)(hrowp + kt * 64);
                short8_t a1 = *(const short8_t*)(hrowp + kt * 64 + 64);
                short8_t w0 = *(const short8_t*)(whb + (size_t)kt * 512);
                short8_t w1 = *(const short8_t*)(whb + (size_t)kt * 512 + 512);
                acc0 = __builtin_amdgcn_mfma_f32_16x16x32_bf16(a0, w0, acc0, 0, 0, 0);
                acc1 = __builtin_amdgcn_mfma_f32_16x16x32_bf16(a1, w1, acc1, 0, 0, 0);
            }
            float4_t cv  = acc0 + acc1;     // h contribution
            float4_t cxv = xacc0 + xacc1;   // x contribution
            if (g < 2) {
                float* cd = (g == 0) ? cz : cr;
                cv += cxv;
#pragma unroll
                for (int rg = 0; rg < 4; ++rg) cd[(quad * 4 + rg) * 16 + lrow] = cv[rg];
            } else {
#pragma unroll
                for (int rg = 0; rg < 4; ++rg) {
                    chn[(quad * 4 + rg) * 16 + lrow] = cv[rg];
                    cxn[(quad * 4 + rg) * 16 + lrow] = cxv[rg];
                }
            }
        } else {
            // partials consumed at distance 2 (signal fires before partial store)
            if (t > 1 && twg < 16) mp_reduce(t - 2);   // overlapped with h-GEMM
        }
        __syncthreads();   // sync C

        // gate update: thread owns (row=tid>>4, col=tid&15)
        float hnew_keep;
        {
            const int urow = tid >> 4;
            float zz = cz[tid] + bz;
            float rr = cr[tid] + br;
            zz = 1.f / (1.f + expf(-zz));
            rr = 1.f / (1.f + expf(-rr));
            const float nn = tanhf(cxn[tid] + bn + rr * chn[tid]);
            const float hold = hloc[tid];
            const float hnew = hold + zz * (nn - hold);
            hloc[tid] = hnew;
            hnew_keep = hnew;
            // gather 8 bf16 across lanes tid..tid+7 (same row), 16B bypass store
            const unsigned short hb = f2bf(hnew);
            unsigned w0 = (unsigned)hb
                        | (((unsigned)__shfl_xor((int)hb, 1) & 0xffffu) << 16);
            // w0 valid (ordered lo,hi) at even lanes
            unsigned w1 = (unsigned)__shfl_xor((int)w0, 2);  // valid at tid%4==0
            unsigned w2 = (unsigned)__shfl_xor((int)w0, 4);  // valid at tid%8==0
            unsigned w3 = (unsigned)__shfl_xor((int)w1, 4);
            if ((tid & 7) == 0) {
                char* dst = (char*)hring + (size_t)(t + 1) * 131072
                          + (size_t)(b0 + urow) * 2048 + twg * 32 + (tid & 8) * 2;
                uint4v pk; pk.x = w0; pk.y = w1; pk.z = w2; pk.w = w3;
                st_bypass_u128(dst, pk);
            }
        }
        __syncthreads();   // sync D: vmcnt(0) drain -> hring stores LLC-visible

        // SIGNAL EARLY: consumers only need hring (drained above). part64 of
        // this step is guarded by NEXT step's signal (drained at next sync A).
        if (tid == 0) {
            __hip_atomic_fetch_add(teamctr, 1u, __ATOMIC_RELAXED,
                                   __HIP_MEMORY_SCOPE_AGENT);
        }

        // mode-head partial (reads full hloc), 16B bypass store.
        // Off the critical path: drains at next-iter sync A.
        if (tid < 128) {
            const int prow = tid >> 3, pm = tid & 7;
            float s = 0.f;
#pragma unroll
            for (int c = 0; c < 16; ++c) s += hloc[prow * 16 + c] * wmlds[c * 8 + pm];
            const unsigned sb = __float_as_uint(s);
            const unsigned p1 = (unsigned)__shfl_xor((int)sb, 1);   // pm^1
            const unsigned p2 = (unsigned)__shfl_xor((int)sb, 2);   // pm^2
            const unsigned p3 = (unsigned)__shfl_xor((int)p1, 2);   // (pm^2)^1
            if ((tid & 3) == 0) {
                char* dst = (char*)part64 + ((size_t)(t % 3) * 4 + team) * 32768
                          + (size_t)twg * 512 + prow * 32 + (pm >> 1) * 8;
                uint4v pk; pk.x = sb; pk.y = p1; pk.z = p2; pk.w = p3;
                st_bypass_u128(dst, pk);
            }
        }

        // 'out' states store off the critical path (normal cached, HW-coalesced)
        out[((size_t)(b0 + (tid >> 4)) * 512 + t) * 1024 + colg] = hnew_keep;
        // NO sync E: next-iter sync A provides the drain + LDS hazard guard
    }

    // tail: drain last partials, final signal, wait, then outputs
    __syncthreads();   // drains part/out stores of t = T-1
    if (tid == 0) {
        __hip_atomic_fetch_add(teamctr, 1u, __ATOMIC_RELAXED,
                               __HIP_MEMORY_SCOPE_AGENT);
        const unsigned tgt = 64u * (unsigned)T_STEPS + 64u;
        while (ld_agent_u32(teamctr) < tgt) { }
    }
    __syncthreads();
    out[HN_OFF + (size_t)(b0 + (tid >> 4)) * 1024 + colg] = hloc[tid];
    if (wave == 3 && twg < 16) {
        mp_reduce(T_STEPS - 2);
        mp_reduce(T_STEPS - 1);
    }
}

// ---- host ------------------------------------------------------------------

extern "C" void kernel_launch(void* const* d_in, const int* in_sizes, int n_in,
                              void* d_out, int out_size, void* d_ws, size_t ws_size,
                              hipStream_t stream) {
    (void)in_sizes; (void)n_in; (void)out_size; (void)ws_size;
    const float* input = (const float*)d_in[0];
    const float* h0    = (const float*)d_in[1];
    const float* Wx    = (const float*)d_in[2];
    const float* Wh    = (const float*)d_in[3];
    const float* bvec  = (const float*)d_in[4];
    const float* Wm    = (const float*)d_in[5];
    const float* bm    = (const float*)d_in[6];
    float* out = (float*)d_out;

    char* ws = (char*)d_ws;
    unsigned short* xbf   = (unsigned short*)(ws + OFF_XBF);
    unsigned short* whswz = (unsigned short*)(ws + OFF_WH);
    unsigned short* wxswz = (unsigned short*)(ws + OFF_WX);
    unsigned short* hring = (unsigned short*)(ws + OFF_HRING);
    unsigned long long* part64 = (unsigned long long*)(ws + OFF_PART);
    unsigned int*   flagp = (unsigned int*)(ws + OFF_CTR);

    (void)hipMemsetAsync(ws + OFF_CTR, 0, SZ_CTR, stream);

    prep_x   <<<16384, 256, 0, stream>>>(input, xbf);
    prep_h0  <<<64,    256, 0, stream>>>(h0, hring);   // ring entry 0
    prep_wh_k<<<1536,  256, 0, stream>>>(Wh, whswz);
    prep_wx_k<<<768,   256, 0, stream>>>(Wx, wxswz);

    (void)hipFuncSetAttribute((const void*)gru_persistent,
                        hipFuncAttributeMaxDynamicSharedMemorySize, SMEM_BYTES);

    void* args[] = {&xbf, &whswz, &wxswz, &hring, &part64, &flagp,
                    (void*)&h0, (void*)&bvec, (void*)&Wm, (void*)&bm, &out};
    (void)hipLaunchCooperativeKernel((void*)gru_persistent, dim3(256), dim3(256),
                               args, (unsigned)SMEM_BYTES, stream);
}

// Round 7
// 2479.879 us; speedup vs baseline: 1.3479x; 1.3479x over previous
//
#include <hip/hip_runtime.h>
#include <hip/hip_bf16.h>

// GRU: B=64 T=512 I=512 H=1024 M=8
// Partition: 4 teams (16 batch rows each) x 64 WGs (16 H-cols each).
// Cross-WG data (hbuf, part) via L1/L2-BYPASS (sc0 sc1) 16B accesses,
// coherent at LLC/MALL. __syncthreads vmcnt(0) drain + relaxed counter
// bump = release semantics. Monotonic per-team counter barrier.
// R6: 16B bypass transport + counter barrier -> 2950us (best).
// R7: L2-routed cached broadcast -> 3137us REGRESSION, reverted (FETCH
//     unchanged -> reads were MALL-served either way; L2 hop adds latency).
// R8 (this round): Wh register-resident. Wh B-frags are step-invariant;
//     re-reading them from LDS each step wasted half the h-GEMM's LDS
//     bandwidth (96 of 192 ds_read_b128/CU/step). Each gate wave now holds
//     its 32 short8 frags in 128 VGPRs (static unrolled indexing). whlds
//     (96KB) removed from LDS entirely (38.6KB total).

typedef __attribute__((ext_vector_type(8))) short short8_t;
typedef __attribute__((ext_vector_type(4))) float float4_t;
typedef __attribute__((ext_vector_type(4))) unsigned int uint4v;

#define T_STEPS 512

// workspace layout (bytes)
#define OFF_XBF  0ull
#define SZ_XBF   (64ull*512*512*2)            // 33,554,432
#define OFF_WH   (OFF_XBF + SZ_XBF)
#define SZ_WH    (64ull*3*32*64*8*2)          // 6,291,456
#define OFF_WX   (OFF_WH + SZ_WH)
#define SZ_WX    (64ull*3*16*64*8*2)          // 3,145,728
#define OFF_HBUF (OFF_WX + SZ_WX)
#define SZ_HBUF  (2ull*64*1024*2)             // 262,144 (2 x [64 rows][2048B])
#define OFF_PART (OFF_HBUF + SZ_HBUF)
#define SZ_PART  (3ull*4*64*16*8*4)           // 393,216
#define OFF_CTR  (OFF_PART + SZ_PART)
#define SZ_CTR   4096ull                      // per-team monotonic ctr @ team*128B

// output layout (fp32 elements)
#define HN_OFF   (64ull*512*1024)             // 33,554,432
#define MP_OFF   (HN_OFF + 64ull*1024)        // 33,619,968

// LDS: cz/cr/chn/cxn 4096 | hloc 1024 | wmlds 512 | hlds 16*2064
#define HLDS_STRIDE 2064                      // 1032 shorts: breaks bank alias
#define SMEM_BYTES (4096 + 1024 + 512 + 16*HLDS_STRIDE)

static __device__ __forceinline__ unsigned short f2bf(float f) {
    __hip_bfloat16 h = __float2bfloat16(f);
    unsigned short u;
    __builtin_memcpy(&u, &h, 2);
    return u;
}
static __device__ __forceinline__ unsigned ld_agent_u32(const unsigned* p) {
    return __hip_atomic_load(p, __ATOMIC_RELAXED, __HIP_MEMORY_SCOPE_AGENT);
}
// 16B LLC-coherent (L1/L2-bypass) store, fire-and-forget (drained by syncthreads)
static __device__ __forceinline__ void st_bypass_u128(void* p, uint4v v) {
    asm volatile("global_store_dwordx4 %0, %1, off sc0 sc1"
                 :: "v"(p), "v"(v) : "memory");
}
// 2x16B LLC-coherent loads, pipelined, one wait
static __device__ __forceinline__ void ld_bypass_2x128(const void* p0, const void* p1,
                                                       uint4v& a, uint4v& b) {
    asm volatile("global_load_dwordx4 %0, %2, off sc0 sc1\n\t"
                 "global_load_dwordx4 %1, %3, off sc0 sc1\n\t"
                 "s_waitcnt vmcnt(0)"
                 : "=&v"(a), "=&v"(b) : "v"(p0), "v"(p1) : "memory");
}

// ---- prep kernels ----------------------------------------------------------

__global__ void prep_x(const float* __restrict__ x, unsigned short* __restrict__ xbf) {
    const size_t i = ((size_t)blockIdx.x * 256 + threadIdx.x) * 4;
    const float4 v = *(const float4*)(x + i);
    ushort4 o = make_ushort4(f2bf(v.x), f2bf(v.y), f2bf(v.z), f2bf(v.w));
    *(ushort4*)(xbf + i) = o;
}

__global__ void prep_h0(const float* __restrict__ h0, unsigned short* __restrict__ hbuf) {
    const size_t i = ((size_t)blockIdx.x * 256 + threadIdx.x) * 4;   // 65,536 elems
    const float4 v = *(const float4*)(h0 + i);
    ushort4 o = make_ushort4(f2bf(v.x), f2bf(v.y), f2bf(v.z), f2bf(v.w));
    *(ushort4*)(hbuf + i) = o;
}

// whswz[((twg*3+g)*32+kt)*64+lane][j] = Wh[kt*32+(lane>>4)*8+j][g*1024+twg*16+(lane&15)]
__global__ void prep_wh_k(const float* __restrict__ Wh, unsigned short* __restrict__ whswz) {
    const int tid = blockIdx.x * 256 + threadIdx.x;   // 393,216 total
    const int lane = tid & 63;
    const int r = tid >> 6;
    const int kt = r & 31;
    const int r2 = r >> 5;            // twg*3+g
    const int g = r2 % 3;
    const int twg = r2 / 3;
    const int col = g * 1024 + twg * 16 + (lane & 15);
    const int k0 = kt * 32 + (lane >> 4) * 8;
    unsigned short tmp[8];
#pragma unroll
    for (int j = 0; j < 8; ++j) tmp[j] = f2bf(Wh[(size_t)(k0 + j) * 3072 + col]);
    ushort4* dst = (ushort4*)(whswz + (size_t)tid * 8);
    dst[0] = make_ushort4(tmp[0], tmp[1], tmp[2], tmp[3]);
    dst[1] = make_ushort4(tmp[4], tmp[5], tmp[6], tmp[7]);
}

__global__ void prep_wx_k(const float* __restrict__ Wx, unsigned short* __restrict__ wxswz) {
    const int tid = blockIdx.x * 256 + threadIdx.x;   // 196,608 total
    const int lane = tid & 63;
    const int r = tid >> 6;
    const int kt = r & 15;
    const int r2 = r >> 4;            // twg*3+g
    const int g = r2 % 3;
    const int twg = r2 / 3;
    const int col = g * 1024 + twg * 16 + (lane & 15);
    const int k0 = kt * 32 + (lane >> 4) * 8;
    unsigned short tmp[8];
#pragma unroll
    for (int j = 0; j < 8; ++j) tmp[j] = f2bf(Wx[(size_t)(k0 + j) * 3072 + col]);
    ushort4* dst = (ushort4*)(wxswz + (size_t)tid * 8);
    dst[0] = make_ushort4(tmp[0], tmp[1], tmp[2], tmp[3]);
    dst[1] = make_ushort4(tmp[4], tmp[5], tmp[6], tmp[7]);
}

// ---- persistent GRU kernel -------------------------------------------------

__global__ void __launch_bounds__(256, 1) gru_persistent(
    const unsigned short* __restrict__ xbf,
    const unsigned short* __restrict__ whswz,
    const unsigned short* __restrict__ wxswz,
    unsigned* __restrict__ hbuf32,
    unsigned long long* __restrict__ part64,
    unsigned int* __restrict__ flags,
    const float* __restrict__ h0,
    const float* __restrict__ bvec,
    const float* __restrict__ wm,
    const float* __restrict__ bm,
    float* __restrict__ out)
{
    extern __shared__ char smem[];
    float* cz    = (float*)smem;                            // [16][16]
    float* cr    = cz + 256;
    float* chn   = cr + 256;
    float* cxn   = chn + 256;
    float* hloc  = cxn + 256;                               // [16][16] fp32 h slice
    float* wmlds = hloc + 256;                              // [16][8]
    char*  hlds  = smem + 4096 + 1024 + 512;                // 16 rows x HLDS_STRIDE

    const int wg   = blockIdx.x;
    const int team = wg & 3;
    const int twg  = wg >> 2;
    const int tid  = threadIdx.x;
    const int wave = tid >> 6;
    const int lane = tid & 63;
    const int quad = lane >> 4;
    const int lrow = lane & 15;
    const int b0   = team * 16;
    const int colg = twg * 16 + (tid & 15);

    const int g = wave;                            // gate id for waves 0..2

    // one-time: Wh B-fragments -> registers (waves 0..2), 128 VGPRs/lane.
    // Static unrolled indexing keeps wreg in registers (no scratch).
    short8_t wreg[32];
    if (wave < 3) {
        const unsigned short* wbase = whswz + ((size_t)(twg * 3 + g) * 2048 + lane) * 8;
#pragma unroll
        for (int kt = 0; kt < 32; ++kt)
            wreg[kt] = *(const short8_t*)(wbase + (size_t)kt * 512);
    }
    if (tid < 128) wmlds[tid] = wm[(twg * 16 + (tid >> 3)) * 8 + (tid & 7)];
    hloc[tid] = h0[(size_t)(b0 + (tid >> 4)) * 1024 + colg];
    const float bz = bvec[colg], br = bvec[1024 + colg], bn = bvec[2048 + colg];
    __syncthreads();

    unsigned int* teamctr = flags + team * 32;      // 128B apart per team

    auto mp_reduce = [&](int tprev) {
        const int p = tprev % 3;
        const int row = twg;                  // caller guards twg<16
        const char* pbase = (const char*)part64
            + ((size_t)p * 4 + team) * 32768 + (size_t)lane * 512 + row * 32;
        uint4v qa, qb;
        ld_bypass_2x128(pbase, pbase + 16, qa, qb);
        float4 va, vb;
        va.x = __uint_as_float(qa.x); va.y = __uint_as_float(qa.y);
        va.z = __uint_as_float(qa.z); va.w = __uint_as_float(qa.w);
        vb.x = __uint_as_float(qb.x); vb.y = __uint_as_float(qb.y);
        vb.z = __uint_as_float(qb.z); vb.w = __uint_as_float(qb.w);
#pragma unroll
        for (int off = 1; off < 64; off <<= 1) {
            va.x += __shfl_xor(va.x, off); va.y += __shfl_xor(va.y, off);
            va.z += __shfl_xor(va.z, off); va.w += __shfl_xor(va.w, off);
            vb.x += __shfl_xor(vb.x, off); vb.y += __shfl_xor(vb.y, off);
            vb.z += __shfl_xor(vb.z, off); vb.w += __shfl_xor(vb.w, off);
        }
        if (lane == 0) {
            float v[8] = {va.x, va.y, va.z, va.w, vb.x, vb.y, vb.z, vb.w};
            float mx = -3.4e38f;
#pragma unroll
            for (int m = 0; m < 8; ++m) { v[m] += bm[m]; mx = fmaxf(mx, v[m]); }
            float s = 0.f;
#pragma unroll
            for (int m = 0; m < 8; ++m) { v[m] = expf(v[m] - mx); s += v[m]; }
            const float inv = 1.f / s;
            float* dst = out + MP_OFF + ((size_t)(b0 + row) * 512 + tprev) * 8;
#pragma unroll
            for (int m = 0; m < 8; ++m) dst[m] = v[m] * inv;
        }
    };

    for (int t = 0; t < T_STEPS; ++t) {
        float4_t acc0 = {0.f,0.f,0.f,0.f}, acc1 = {0.f,0.f,0.f,0.f};
        float4_t xacc0 = {0.f,0.f,0.f,0.f}, xacc1 = {0.f,0.f,0.f,0.f};

        // x-GEMM (h-independent) BEFORE the barrier wait — hides sync latency
        if (wave < 3) {
            const unsigned short* xrow = xbf + ((size_t)(b0 + lrow) * 512 + t) * 512 + quad * 8;
            const unsigned short* wxb  = wxswz + ((size_t)(twg * 3 + g) * 16 * 64 + lane) * 8;
#pragma unroll
            for (int kt = 0; kt < 16; kt += 2) {
                short8_t a0 = *(const short8_t*)(xrow + kt * 32);
                short8_t a1 = *(const short8_t*)(xrow + kt * 32 + 32);
                short8_t w0 = *(const short8_t*)(wxb + (size_t)kt * 512);
                short8_t w1 = *(const short8_t*)(wxb + (size_t)kt * 512 + 512);
                xacc0 = __builtin_amdgcn_mfma_f32_16x16x32_bf16(a0, w0, xacc0, 0, 0, 0);
                xacc1 = __builtin_amdgcn_mfma_f32_16x16x32_bf16(a1, w1, xacc1, 0, 0, 0);
            }
        }

        // team barrier: single monotonic counter, 1 polling lane per WG
        if (t > 0 && tid == 0) {
            const unsigned tgt = 64u * (unsigned)t;
            while (ld_agent_u32(teamctr) < tgt) { }
        }
        __syncthreads();   // sync A (also drains prev-step part/out stores)

        // stage this team's h slice (16 rows x 2048B) into LDS:
        // 8 pipelined 16B bypass loads per thread, one vmcnt wait, 16B LDS writes
        {
            const char* sbase = (const char*)hbuf32 + (size_t)(t & 1) * 131072
                              + (size_t)b0 * 2048 + (size_t)tid * 16;
            uint4v t0,t1,t2,t3,t4,t5,t6,t7;
            asm volatile(
                "global_load_dwordx4 %0, %8, off sc0 sc1\n\t"
                "global_load_dwordx4 %1, %9, off sc0 sc1\n\t"
                "global_load_dwordx4 %2, %10, off sc0 sc1\n\t"
                "global_load_dwordx4 %3, %11, off sc0 sc1\n\t"
                "global_load_dwordx4 %4, %12, off sc0 sc1\n\t"
                "global_load_dwordx4 %5, %13, off sc0 sc1\n\t"
                "global_load_dwordx4 %6, %14, off sc0 sc1\n\t"
                "global_load_dwordx4 %7, %15, off sc0 sc1\n\t"
                "s_waitcnt vmcnt(0)"
                : "=&v"(t0), "=&v"(t1), "=&v"(t2), "=&v"(t3),
                  "=&v"(t4), "=&v"(t5), "=&v"(t6), "=&v"(t7)
                : "v"(sbase), "v"(sbase + 4096), "v"(sbase + 8192), "v"(sbase + 12288),
                  "v"(sbase + 16384), "v"(sbase + 20480), "v"(sbase + 24576), "v"(sbase + 28672)
                : "memory");
            // global offset of t_i = tid*16 + i*4096 -> row = i*2 + (tid>>7),
            // col byte = (tid&127)*16  (2048B per row)
            char* d = hlds + (tid >> 7) * HLDS_STRIDE + (tid & 127) * 16;
            *(uint4v*)(d + 0 * 2 * HLDS_STRIDE) = t0;
            *(uint4v*)(d + 1 * 2 * HLDS_STRIDE) = t1;
            *(uint4v*)(d + 2 * 2 * HLDS_STRIDE) = t2;
            *(uint4v*)(d + 3 * 2 * HLDS_STRIDE) = t3;
            *(uint4v*)(d + 4 * 2 * HLDS_STRIDE) = t4;
            *(uint4v*)(d + 5 * 2 * HLDS_STRIDE) = t5;
            *(uint4v*)(d + 6 * 2 * HLDS_STRIDE) = t6;
            *(uint4v*)(d + 7 * 2 * HLDS_STRIDE) = t7;
        }
        __syncthreads();   // sync B

        if (wave < 3) {
            // h-GEMM: A-frags from padded LDS, B-frags REGISTER-RESIDENT
            const char* hrowp = hlds + lrow * HLDS_STRIDE + quad * 16;
#pragma unroll
            for (int kt = 0; kt < 32; kt += 2) {
                short8_t a0 = *(const short8_t*)(hrowp + kt * 64);
                short8_t a1 = *(const short8_t*)(hrowp + kt * 64 + 64);
                acc0 = __builtin_amdgcn_mfma_f32_16x16x32_bf16(a0, wreg[kt],     acc0, 0, 0, 0);
                acc1 = __builtin_amdgcn_mfma_f32_16x16x32_bf16(a1, wreg[kt + 1], acc1, 0, 0, 0);
            }
            float4_t cv  = acc0 + acc1;     // h contribution
            float4_t cxv = xacc0 + xacc1;   // x contribution
            if (g < 2) {
                float* cd = (g == 0) ? cz : cr;
                cv += cxv;
#pragma unroll
                for (int rg = 0; rg < 4; ++rg) cd[(quad * 4 + rg) * 16 + lrow] = cv[rg];
            } else {
#pragma unroll
                for (int rg = 0; rg < 4; ++rg) {
                    chn[(quad * 4 + rg) * 16 + lrow] = cv[rg];
                    cxn[(quad * 4 + rg) * 16 + lrow] = cxv[rg];
                }
            }
        } else {
            // partials consumed at distance 2 (signal fires before partial store)
            if (t > 1 && twg < 16) mp_reduce(t - 2);   // overlapped with h-GEMM
        }
        __syncthreads();   // sync C

        // gate update: thread owns (row=tid>>4, col=tid&15)
        float hnew_keep;
        {
            const int urow = tid >> 4;
            float zz = cz[tid] + bz;
            float rr = cr[tid] + br;
            zz = 1.f / (1.f + expf(-zz));
            rr = 1.f / (1.f + expf(-rr));
            const float nn = tanhf(cxn[tid] + bn + rr * chn[tid]);
            const float hold = hloc[tid];
            const float hnew = hold + zz * (nn - hold);
            hloc[tid] = hnew;
            hnew_keep = hnew;
            // gather 8 bf16 across lanes tid..tid+7 (same row), 16B bypass store
            const unsigned short hb = f2bf(hnew);
            unsigned w0 = (unsigned)hb
                        | (((unsigned)__shfl_xor((int)hb, 1) & 0xffffu) << 16);
            // w0 valid (ordered lo,hi) at even lanes
            unsigned w1 = (unsigned)__shfl_xor((int)w0, 2);  // valid at tid%4==0
            unsigned w2 = (unsigned)__shfl_xor((int)w0, 4);  // valid at tid%8==0
            unsigned w3 = (unsigned)__shfl_xor((int)w1, 4);
            if ((tid & 7) == 0) {
                char* dst = (char*)hbuf32 + (size_t)((t + 1) & 1) * 131072
                          + (size_t)(b0 + urow) * 2048 + twg * 32 + (tid & 8) * 2;
                uint4v pk; pk.x = w0; pk.y = w1; pk.z = w2; pk.w = w3;
                st_bypass_u128(dst, pk);
            }
        }
        __syncthreads();   // sync D: vmcnt(0) drain -> hbuf stores LLC-visible

        // SIGNAL EARLY: consumers only need hbuf (drained above). part64 of this
        // step is guarded by NEXT step's signal (drained at next sync A).
        if (tid == 0) {
            __hip_atomic_fetch_add(teamctr, 1u, __ATOMIC_RELAXED,
                                   __HIP_MEMORY_SCOPE_AGENT);
        }

        // mode-head partial (reads full hloc), 16B bypass store.
        // Off the critical path: drains at next-iter sync A.
        if (tid < 128) {
            const int prow = tid >> 3, pm = tid & 7;
            float s = 0.f;
#pragma unroll
            for (int c = 0; c < 16; ++c) s += hloc[prow * 16 + c] * wmlds[c * 8 + pm];
            const unsigned sb = __float_as_uint(s);
            const unsigned p1 = (unsigned)__shfl_xor((int)sb, 1);   // pm^1
            const unsigned p2 = (unsigned)__shfl_xor((int)sb, 2);   // pm^2
            const unsigned p3 = (unsigned)__shfl_xor((int)p1, 2);   // (pm^2)^1
            if ((tid & 3) == 0) {
                char* dst = (char*)part64 + ((size_t)(t % 3) * 4 + team) * 32768
                          + (size_t)twg * 512 + prow * 32 + (pm >> 1) * 8;
                uint4v pk; pk.x = sb; pk.y = p1; pk.z = p2; pk.w = p3;
                st_bypass_u128(dst, pk);
            }
        }

        // 'out' states store off the critical path (normal cached, HW-coalesced)
        out[((size_t)(b0 + (tid >> 4)) * 512 + t) * 1024 + colg] = hnew_keep;
        // NO sync E: next-iter sync A provides the drain + LDS hazard guard
    }

    // tail: drain last partials, final signal, wait, then outputs
    __syncthreads();   // drains part/out stores of t = T-1
    if (tid == 0) {
        __hip_atomic_fetch_add(teamctr, 1u, __ATOMIC_RELAXED,
                               __HIP_MEMORY_SCOPE_AGENT);
        const unsigned tgt = 64u * (unsigned)T_STEPS + 64u;
        while (ld_agent_u32(teamctr) < tgt) { }
    }
    __syncthreads();
    out[HN_OFF + (size_t)(b0 + (tid >> 4)) * 1024 + colg] = hloc[tid];
    if (wave == 3 && twg < 16) {
        mp_reduce(T_STEPS - 2);
        mp_reduce(T_STEPS - 1);
    }
}

// ---- host ------------------------------------------------------------------

extern "C" void kernel_launch(void* const* d_in, const int* in_sizes, int n_in,
                              void* d_out, int out_size, void* d_ws, size_t ws_size,
                              hipStream_t stream) {
    (void)in_sizes; (void)n_in; (void)out_size; (void)ws_size;
    const float* input = (const float*)d_in[0];
    const float* h0    = (const float*)d_in[1];
    const float* Wx    = (const float*)d_in[2];
    const float* Wh    = (const float*)d_in[3];
    const float* bvec  = (const float*)d_in[4];
    const float* Wm    = (const float*)d_in[5];
    const float* bm    = (const float*)d_in[6];
    float* out = (float*)d_out;

    char* ws = (char*)d_ws;
    unsigned short* xbf   = (unsigned short*)(ws + OFF_XBF);
    unsigned short* whswz = (unsigned short*)(ws + OFF_WH);
    unsigned short* wxswz = (unsigned short*)(ws + OFF_WX);
    unsigned*       hbuf32= (unsigned*)(ws + OFF_HBUF);
    unsigned long long* part64 = (unsigned long long*)(ws + OFF_PART);
    unsigned int*   flagp = (unsigned int*)(ws + OFF_CTR);

    (void)hipMemsetAsync(ws + OFF_CTR, 0, SZ_CTR, stream);

    prep_x   <<<16384, 256, 0, stream>>>(input, xbf);
    prep_h0  <<<64,    256, 0, stream>>>(h0, (unsigned short*)(ws + OFF_HBUF));
    prep_wh_k<<<1536,  256, 0, stream>>>(Wh, whswz);
    prep_wx_k<<<768,   256, 0, stream>>>(Wx, wxswz);

    (void)hipFuncSetAttribute((const void*)gru_persistent,
                        hipFuncAttributeMaxDynamicSharedMemorySize, SMEM_BYTES);

    void* args[] = {&xbf, &whswz, &wxswz, &hbuf32, &part64, &flagp,
                    (void*)&h0, (void*)&bvec, (void*)&Wm, (void*)&bm, &out};
    (void)hipLaunchCooperativeKernel((void*)gru_persistent, dim3(256), dim3(256),
                               args, (unsigned)SMEM_BYTES, stream);
}